// Round 4
// baseline (768.468 us; speedup 1.0000x reference)
//
#include <hip/hip_runtime.h>
#include <cstdint>
#include <cstddef>

typedef __attribute__((ext_vector_type(4))) int   i32x4;
typedef __attribute__((ext_vector_type(4))) float f32x4;

// Problem dims (fixed by setup_inputs: B=8, S=2048, K=4096, O=4096)
#define M_DIM 16384
#define N_DIM 4096
#define K_DIM 4096
#define NT    (K_DIM / 128)   // 32 K-tiles of 128 int8 (= 2 MFMA K-steps each)

// ---------------------------------------------------------------------------
// quantize x (per-tensor): xq = clip(rint(x/s)+zp, -128,127) - zp
// ---------------------------------------------------------------------------
__global__ __launch_bounds__(256) void quant_x_kernel(
    const float* __restrict__ x,
    const float* __restrict__ act_scale,
    const int*   __restrict__ act_zp,
    signed char* __restrict__ xq)
{
    int idx = blockIdx.x * 256 + threadIdx.x;      // one thread per 16 elems
    float s   = act_scale[0];
    float zpf = (float)act_zp[0];
    const f32x4* xp = (const f32x4*)(x + (size_t)idx * 16);
    union { signed char c[16]; i32x4 v; } u;
#pragma unroll
    for (int j = 0; j < 4; ++j) {
        f32x4 v = xp[j];
#pragma unroll
        for (int e = 0; e < 4; ++e) {
            float q = rintf(v[e] / s) + zpf;          // round-half-even like np.round
            q = fminf(fmaxf(q, -128.f), 127.f);
            u.c[j * 4 + e] = (signed char)(int)(q - zpf);
        }
    }
    *(i32x4*)(xq + (size_t)idx * 16) = u.v;
}

// ---------------------------------------------------------------------------
// quantize weight (per-output-row scale/zp). K_DIM=4096 -> 256 threads/row.
// ---------------------------------------------------------------------------
__global__ __launch_bounds__(256) void quant_w_kernel(
    const float* __restrict__ w,
    const float* __restrict__ wscale,
    const int*   __restrict__ wzp,
    signed char* __restrict__ wq)
{
    int idx = blockIdx.x * 256 + threadIdx.x;
    int row = idx >> 8;                             // 4096/16 = 256 chunks per row
    float s   = wscale[row];
    float zpf = (float)wzp[row];
    const f32x4* wp = (const f32x4*)(w + (size_t)idx * 16);
    union { signed char c[16]; i32x4 v; } u;
#pragma unroll
    for (int j = 0; j < 4; ++j) {
        f32x4 v = wp[j];
#pragma unroll
        for (int e = 0; e < 4; ++e) {
            float q = rintf(v[e] / s) + zpf;
            q = fminf(fmaxf(q, -128.f), 127.f);
            u.c[j * 4 + e] = (signed char)(int)(q - zpf);
        }
    }
    *(i32x4*)(wq + (size_t)idx * 16) = u.v;
}

// ---------------------------------------------------------------------------
// int8 GEMM, 256x256, 4 phases/K-tile, ds_reads SOFTWARE-PIPELINED one phase
// ahead (phase p issues reads for quad p+1; MFMA p's operands were read in
// phase p-1 and drain under p-1's MFMA cluster -> LDS port overlaps matrix
// pipe). ONE barrier per phase (post-MFMA). Race analysis: every STAGE
// targets the other buffer or a B-region whose readers lgkm-drained before a
// barrier preceding the stage (max wave skew = 1 phase at rendezvous).
//
// Per tile t (quads q00,q01,q11,q10; A0c/B0c = current a0/b0 reg set):
//  P0: read b1(4);        stage(t+1,A0);  mfma q00(A0c,B0c);            bar
//  P1: read a1(8);        stage(t+1,A1);  mfma q01(A0c,b1);             bar
//  P2:                    stage(t+2,B0);  mfma q11(a1,b1);   vmcnt(2);  bar
//  P3: read A0n,B0n(12) [next tile, other buf]; stage(t+2,B1);
//                                         mfma q10(a1,B0c);             bar
// Tile-boundary drain rotated into P2: vmcnt(2) leaves only B0(t+2) in
// flight -> all of tile t+1 landed before P3's preload reads it.
// a0/b0 register sets alternate per tile (named sets, loop unrolled x2).
// T2 swizzle (3-bit, conflict-free, verified round 3) unchanged.
// ---------------------------------------------------------------------------
__global__ __launch_bounds__(512, 2) void gemm_i8_256(
    const signed char* __restrict__ Aq,
    const signed char* __restrict__ Bq,
    const float* __restrict__ bias,
    const float* __restrict__ act_scale,
    const float* __restrict__ wscale,
    float* __restrict__ out)
{
    __shared__ signed char lds[131072];   // 128 KiB -> 1 block/CU, 2 waves/SIMD

    const int nbn = N_DIM / 256;                 // 16
    const int nwg = (M_DIM / 256) * nbn;         // 1024, %8==0 -> simple swizzle ok
    int bid = blockIdx.x;
    int wg  = (bid & 7) * (nwg >> 3) + (bid >> 3);   // T1 XCD swizzle, bijective
    int bm  = wg / nbn;
    int bn  = wg % nbn;

    int tid  = threadIdx.x;
    int wave = tid >> 6;
    int lane = tid & 63;
    int wm_i = wave >> 2;      // 0..1
    int wn_i = wave & 3;       // 0..3

    const signed char* Ag = Aq + (size_t)bm * 256 * K_DIM;
    const signed char* Bg = Bq + (size_t)bn * 256 * K_DIM;

    // staging: linear LDS dest; inverse-swizzled per-lane GLOBAL source.
    int srow = tid >> 3;
    int scol = ((tid & 7) * 16) ^ ((srow & 7) << 4);
    int soff0 = srow * K_DIM + scol;            // rows 0..63 of half-tile
    int soff1 = (srow + 64) * K_DIM + scol;     // rows 64..127

    // reader fragment bases with 3-bit swizzle folded in (row&7 == lane&7).
    int lk = (lane >> 4) * 16;
    int xm = (lane & 7) << 4;
    int arow = wm_i * 128 + (lane & 15);
    int brow = wn_i * 64 + (lane & 15);
    int ab0 = (arow * 128 + lk) ^ xm;                    // kk=0
    int ab1 = (arow * 128 + lk + 64) ^ xm;               // kk=1
    int bb0 = (32768 + brow * 128 + lk) ^ xm;
    int bb1 = (32768 + brow * 128 + lk + 64) ^ xm;

    // pos: 0=B-half0, 1=B-half1, 2=A-half0, 3=A-half1
#define STAGE(tile, pos) do {                                                        \
    const signed char* _src = (((pos) < 2)                                           \
        ? (Bg + (size_t)((pos) * 128) * K_DIM)                                       \
        : (Ag + (size_t)(((pos) - 2) * 128) * K_DIM)) + (size_t)(tile) * 128;        \
    int _ldso = ((tile) & 1) * 65536                                                 \
              + (((pos) < 2) ? (32768 + (pos) * 16384) : (((pos) - 2) * 16384))      \
              + wave * 1024;                                                         \
    __builtin_amdgcn_global_load_lds(                                                \
        (const __attribute__((address_space(1))) void*)(_src + soff0),               \
        (__attribute__((address_space(3))) void*)(lds + _ldso), 16, 0, 0);           \
    __builtin_amdgcn_global_load_lds(                                                \
        (const __attribute__((address_space(1))) void*)(_src + soff1),               \
        (__attribute__((address_space(3))) void*)(lds + _ldso + 8192), 16, 0, 0);    \
} while (0)

    i32x4 acc[8][4] = {};
    i32x4 a0E[4][2], b0E[2][2], a0O[4][2], b0O[2][2];
    i32x4 a1[4][2], b1[2][2];

    // mfma quad: 4 mf x 2 nf x 2 kk into acc[mo..mo+3][no..no+1]
#define MFMA_Q(AF, BF, mo, no) do {                                                  \
    _Pragma("unroll")                                                                \
    for (int mf = 0; mf < 4; ++mf)                                                   \
        _Pragma("unroll")                                                            \
        for (int nf = 0; nf < 2; ++nf)                                               \
            _Pragma("unroll")                                                        \
            for (int kk = 0; kk < 2; ++kk)                                           \
                acc[(mo) + mf][(no) + nf] = __builtin_amdgcn_mfma_i32_16x16x64_i8(   \
                    AF[mf][kk], BF[nf][kk], acc[(mo) + mf][(no) + nf], 0, 0, 0);     \
} while (0)

#define READ_B1(buf) do {                                                            \
    _Pragma("unroll")                                                                \
    for (int nf = 0; nf < 2; ++nf) {                                                 \
        b1[nf][0] = *(const i32x4*)((buf) + bb0 + (2 + nf) * 2048);                  \
        b1[nf][1] = *(const i32x4*)((buf) + bb1 + (2 + nf) * 2048);                  \
    }                                                                                \
} while (0)

#define READ_A1(buf) do {                                                            \
    _Pragma("unroll")                                                                \
    for (int mf = 0; mf < 4; ++mf) {                                                 \
        a1[mf][0] = *(const i32x4*)((buf) + ab0 + (4 + mf) * 2048);                  \
        a1[mf][1] = *(const i32x4*)((buf) + ab1 + (4 + mf) * 2048);                  \
    }                                                                                \
} while (0)

#define READ_A0B0(buf, A0, B0) do {                                                  \
    _Pragma("unroll")                                                                \
    for (int mf = 0; mf < 4; ++mf) {                                                 \
        A0[mf][0] = *(const i32x4*)((buf) + ab0 + mf * 2048);                        \
        A0[mf][1] = *(const i32x4*)((buf) + ab1 + mf * 2048);                        \
    }                                                                                \
    _Pragma("unroll")                                                                \
    for (int nf = 0; nf < 2; ++nf) {                                                 \
        B0[nf][0] = *(const i32x4*)((buf) + bb0 + nf * 2048);                        \
        B0[nf][1] = *(const i32x4*)((buf) + bb1 + nf * 2048);                        \
    }                                                                                \
} while (0)

#define TILE_BODY(t, bufc, bufn, A0c, B0c, A0n, B0n) do {                            \
    /* P0 */                                                                         \
    READ_B1(bufc);                                                                   \
    if ((t) + 1 < NT) STAGE((t) + 1, 2);                                             \
    __builtin_amdgcn_s_setprio(1);  MFMA_Q(A0c, B0c, 0, 0);                          \
    __builtin_amdgcn_s_setprio(0);  __builtin_amdgcn_s_barrier();                    \
    /* P1 */                                                                         \
    READ_A1(bufc);                                                                   \
    if ((t) + 1 < NT) STAGE((t) + 1, 3);                                             \
    __builtin_amdgcn_s_setprio(1);  MFMA_Q(A0c, b1, 0, 2);                           \
    __builtin_amdgcn_s_setprio(0);  __builtin_amdgcn_s_barrier();                    \
    /* P2 */                                                                         \
    if ((t) + 2 < NT) STAGE((t) + 2, 0);                                             \
    __builtin_amdgcn_s_setprio(1);  MFMA_Q(a1, b1, 4, 2);                            \
    __builtin_amdgcn_s_setprio(0);                                                   \
    if ((t) < NT - 2)       asm volatile("s_waitcnt vmcnt(2)" ::: "memory");         \
    else if ((t) == NT - 2) asm volatile("s_waitcnt vmcnt(0)" ::: "memory");         \
    __builtin_amdgcn_s_barrier();                                                    \
    /* P3 */                                                                         \
    if ((t) + 1 < NT) READ_A0B0(bufn, A0n, B0n);                                     \
    if ((t) + 2 < NT) STAGE((t) + 2, 1);                                             \
    __builtin_amdgcn_s_setprio(1);  MFMA_Q(a1, B0c, 4, 0);                           \
    __builtin_amdgcn_s_setprio(0);  __builtin_amdgcn_s_barrier();                    \
} while (0)

    // prologue: tile0 fully + tile1 B0 (10 loads/wave in flight)
    STAGE(0, 0); STAGE(0, 1); STAGE(0, 2); STAGE(0, 3);
    STAGE(1, 0);
    asm volatile("s_waitcnt vmcnt(2)" ::: "memory");   // tile0's 8 loads landed
    __builtin_amdgcn_s_barrier();
    // P3-role of "tile -1": preload tile0 frags, stage tile1 B1
    READ_A0B0(lds, a0E, b0E);
    STAGE(1, 1);
    __builtin_amdgcn_s_barrier();

    for (int tt = 0; tt < NT; tt += 2) {
        TILE_BODY(tt,     lds,         lds + 65536, a0E, b0E, a0O, b0O);
        TILE_BODY(tt + 1, lds + 65536, lds,         a0O, b0O, a0E, b0E);
    }
#undef TILE_BODY
#undef READ_A0B0
#undef READ_A1
#undef READ_B1
#undef MFMA_Q
#undef STAGE

    // epilogue: out = acc * (sa * sw[o]) + bias[o]
    float sa = act_scale[0];
    int colb = lane & 15;
    int rsub = (lane >> 4) * 4;
#pragma unroll
    for (int nf = 0; nf < 4; ++nf) {
        int o = bn * 256 + wn_i * 64 + nf * 16 + colb;
        float sw = sa * wscale[o];
        float bv = bias[o];
#pragma unroll
        for (int mf = 0; mf < 8; ++mf) {
            int grow = bm * 256 + wm_i * 128 + mf * 16 + rsub;
#pragma unroll
            for (int r = 0; r < 4; ++r)
                out[(size_t)(grow + r) * N_DIM + o] = (float)acc[mf][nf][r] * sw + bv;
        }
    }
}

// ---------------------------------------------------------------------------
// insurance fallback if ws_size < 80MB (should never trigger)
// ---------------------------------------------------------------------------
__global__ void fallback_kernel(
    const float* __restrict__ x, const float* __restrict__ w,
    const float* __restrict__ bias,
    const float* __restrict__ act_scale, const float* __restrict__ wscale,
    const int* __restrict__ act_zp, const int* __restrict__ wzp,
    float* __restrict__ out)
{
    size_t idx = (size_t)blockIdx.x * blockDim.x + threadIdx.x;
    if (idx >= (size_t)M_DIM * N_DIM) return;
    int m = (int)(idx >> 12);
    int o = (int)(idx & 4095);
    float sx = act_scale[0], zx = (float)act_zp[0];
    float sw = wscale[o],    zw = (float)wzp[o];
    float acc = 0.f;
    for (int k = 0; k < K_DIM; ++k) {
        float qx = fminf(fmaxf(rintf(x[(size_t)m * K_DIM + k] / sx) + zx, -128.f), 127.f) - zx;
        float qw = fminf(fmaxf(rintf(w[(size_t)o * K_DIM + k] / sw) + zw, -128.f), 127.f) - zw;
        acc += (qx * sx) * (qw * sw);
    }
    out[idx] = acc + bias[o];
}

// ---------------------------------------------------------------------------
extern "C" void kernel_launch(void* const* d_in, const int* in_sizes, int n_in,
                              void* d_out, int out_size, void* d_ws, size_t ws_size,
                              hipStream_t stream)
{
    const float* x    = (const float*)d_in[0];
    const float* w    = (const float*)d_in[1];
    const float* bias = (const float*)d_in[2];
    const float* asc  = (const float*)d_in[3];
    const float* wsc  = (const float*)d_in[4];
    const int*   azp  = (const int*)d_in[5];
    const int*   wzp  = (const int*)d_in[6];
    float* out = (float*)d_out;

    size_t xq_bytes = (size_t)M_DIM * K_DIM;   // 64 MiB
    size_t wq_bytes = (size_t)N_DIM * K_DIM;   // 16 MiB

    if (ws_size < xq_bytes + wq_bytes) {
        int total = M_DIM * N_DIM;
        fallback_kernel<<<(total + 255) / 256, 256, 0, stream>>>(
            x, w, bias, asc, wsc, azp, wzp, out);
        return;
    }

    signed char* xq = (signed char*)d_ws;
    signed char* wq = (signed char*)d_ws + xq_bytes;

    quant_x_kernel<<<(M_DIM * (K_DIM / 16)) / 256, 256, 0, stream>>>(x, asc, azp, xq);
    quant_w_kernel<<<(N_DIM * (K_DIM / 16)) / 256, 256, 0, stream>>>(w, wsc, wzp, wq);
    gemm_i8_256<<<(M_DIM / 256) * (N_DIM / 256), 512, 0, stream>>>(
        xq, wq, bias, asc, wsc, out);
}

// Round 7
// 374.433 us; speedup vs baseline: 2.0524x; 2.0524x over previous
//
#include <hip/hip_runtime.h>
#include <cstdint>
#include <cstddef>

typedef __attribute__((ext_vector_type(4))) int   i32x4;
typedef __attribute__((ext_vector_type(4))) float f32x4;

// Problem dims (fixed by setup_inputs: B=8, S=2048, K=4096, O=4096)
#define M_DIM 16384
#define N_DIM 4096
#define K_DIM 4096
#define NT    (K_DIM / 128)   // 32 K-tiles of 128 int8 (= 2 MFMA K-steps each)

// Compiler-fenced barrier (full memory fence at each rendezvous).
#define BARRIER() asm volatile("s_barrier" ::: "memory")

// ---------------------------------------------------------------------------
// quantize x (per-tensor): xq = clip(rint(x/s)+zp, -128,127) - zp
// ---------------------------------------------------------------------------
__global__ __launch_bounds__(256) void quant_x_kernel(
    const float* __restrict__ x,
    const float* __restrict__ act_scale,
    const int*   __restrict__ act_zp,
    signed char* __restrict__ xq)
{
    int idx = blockIdx.x * 256 + threadIdx.x;      // one thread per 16 elems
    float s   = act_scale[0];
    float zpf = (float)act_zp[0];
    const f32x4* xp = (const f32x4*)(x + (size_t)idx * 16);
    union { signed char c[16]; i32x4 v; } u;
#pragma unroll
    for (int j = 0; j < 4; ++j) {
        f32x4 v = xp[j];
#pragma unroll
        for (int e = 0; e < 4; ++e) {
            float q = rintf(v[e] / s) + zpf;          // round-half-even like np.round
            q = fminf(fmaxf(q, -128.f), 127.f);
            u.c[j * 4 + e] = (signed char)(int)(q - zpf);
        }
    }
    *(i32x4*)(xq + (size_t)idx * 16) = u.v;
}

// ---------------------------------------------------------------------------
// quantize weight (per-output-row scale/zp). K_DIM=4096 -> 256 threads/row.
// ---------------------------------------------------------------------------
__global__ __launch_bounds__(256) void quant_w_kernel(
    const float* __restrict__ w,
    const float* __restrict__ wscale,
    const int*   __restrict__ wzp,
    signed char* __restrict__ wq)
{
    int idx = blockIdx.x * 256 + threadIdx.x;
    int row = idx >> 8;                             // 4096/16 = 256 chunks per row
    float s   = wscale[row];
    float zpf = (float)wzp[row];
    const f32x4* wp = (const f32x4*)(w + (size_t)idx * 16);
    union { signed char c[16]; i32x4 v; } u;
#pragma unroll
    for (int j = 0; j < 4; ++j) {
        f32x4 v = wp[j];
#pragma unroll
        for (int e = 0; e < 4; ++e) {
            float q = rintf(v[e] / s) + zpf;
            q = fminf(fmaxf(q, -128.f), 127.f);
            u.c[j * 4 + e] = (signed char)(int)(q - zpf);
        }
    }
    *(i32x4*)(wq + (size_t)idx * 16) = u.v;
}

// ---------------------------------------------------------------------------
// int8 GEMM 256x256, one-phase read-ahead, WAVE-UNIFORM staging regions.
//
// ROUNDS 5/6 BUG (fixed here): register set <-> staged half was PER-WAVE
// (wm_i=1's "a0" sat in the A1 staging region, still in flight at its read).
// Fix: repack LDS so each reg set is one contiguous region for ALL waves:
//   LDS A rows: [0,64)=gA 0-63 (wm0 a0) | [64,128)=gA 128-191 (wm1 a0)
//               | [128,192)=gA 64-127 (wm0 a1) | [192,256)=gA 192-255 (wm1 a1)
//   LDS B rows: [32g,32g+32)=gB 64g+0-31 (b0, g=wn_i) ; +128 rows same for
//               b1 (gB 64g+32-63).
// Stage-side only the global ROW map changes (per-lane source is free);
// swizzle keys on row&7 which all maps preserve -> conflict-free XOR intact.
//
// Schedule per tile t (quads q00,q01,q11,q10):
//  P0: read b1(buf t);  STAGE(t+1,A0); q00(a0,b0); [t==NT-1?vmcnt0:vmcnt6]; bar
//  P1: read a1(buf t);  STAGE(t+1,A1); q01(a0,b1); [t<NT-1: vmcnt(2)];      bar
//  P2: read a0(buf t+1);STAGE(t+2,B0); q11(a1,b1);                          bar
//  P3: STAGE(t+2,B1);   q10(a1,b0); sched_barrier; read b0(buf t+1);        bar
// RAW (all reg sets now wave-uniform regions):
//   a1(t) needs SA1(t)@P1(t-1): end-P0(t) vmcnt(6) [6 newer loads in flight]
//   a0(t+1) needs SA0(t+1)@P0(t): end-P1(t) vmcnt(2) [leaves SA1(t+1) only]
//   b0(t+1)@P3(t) needs SB0(t+1)@P2(t-1): retired by end-P1's vmcnt(2)
//   b1(t)@P0(t) needs SB1(t)@P3(t-2): retired by end-P1(t-1)'s vmcnt(2)
// WAR: each STAGE's target region's last ds_reads complete (lgkm before
// consuming MFMA) >=2 barriers before the stage issues. Verified per region.
// Registers: 96 VGPR frags + 128 acc (round-3 footprint, no spill).
// ---------------------------------------------------------------------------
__global__ __launch_bounds__(512, 2) void gemm_i8_256(
    const signed char* __restrict__ Aq,
    const signed char* __restrict__ Bq,
    const float* __restrict__ bias,
    const float* __restrict__ act_scale,
    const float* __restrict__ wscale,
    float* __restrict__ out)
{
    __shared__ signed char lds[131072];   // 2 dbuf x (A 32KB + B 32KB)

    const int nbn = N_DIM / 256;                 // 16
    const int nwg = (M_DIM / 256) * nbn;         // 1024, %8==0 -> simple swizzle ok
    int bid = blockIdx.x;
    int wg  = (bid & 7) * (nwg >> 3) + (bid >> 3);   // T1 XCD swizzle, bijective
    int bm  = wg / nbn;
    int bn  = wg % nbn;

    int tid  = threadIdx.x;
    int wave = tid >> 6;
    int lane = tid & 63;
    int wm_i = wave >> 2;      // 0..1
    int wn_i = wave & 3;       // 0..3

    const signed char* Ag = Aq + (size_t)bm * 256 * K_DIM;
    const signed char* Bg = Bq + (size_t)bn * 256 * K_DIM;

    // ---- staging sources (linear LDS dest; per-lane global row/col) --------
    int srow = tid >> 3;                               // LDS row within chunk
    int scol = ((tid & 7) * 16) ^ ((srow & 7) << 4);   // inverse swizzle col
    int brmap = srow + (srow & 32);                    // B group interleave
    // chunk source offsets (row*K + col); chunk = 64 LDS rows = 8192 B
    int sA0a = srow * K_DIM + scol;                    // LDS A rows 0-63
    int sA0b = (srow + 128) * K_DIM + scol;            // LDS A rows 64-127
    int sA1a = (srow + 64) * K_DIM + scol;             // LDS A rows 128-191
    int sA1b = (srow + 192) * K_DIM + scol;            // LDS A rows 192-255
    int sB0a = brmap * K_DIM + scol;                   // LDS B rows 0-63
    int sB0b = (brmap + 128) * K_DIM + scol;           // LDS B rows 64-127
    int sB1a = (brmap + 32) * K_DIM + scol;            // LDS B rows 128-191
    int sB1b = (brmap + 160) * K_DIM + scol;           // LDS B rows 192-255

    // ---- reader fragment bases (wave-uniform regions, swizzle folded) ------
    int lk = (lane >> 4) * 16;
    int xm = (lane & 7) << 4;
    int lr = lane & 15;
    int ab0 = (((wm_i * 64 + lr) * 128) + lk) ^ xm;          // a0, kk=0
    int ab1 = (((wm_i * 64 + lr) * 128) + lk + 64) ^ xm;     // a0, kk=1
    int bb0 = (32768 + ((wn_i * 32 + lr) * 128) + lk) ^ xm;  // b0, kk=0
    int bb1 = (32768 + ((wn_i * 32 + lr) * 128) + lk + 64) ^ xm;
    // a1 = a0 base + 16384; b1 = b0 base + 16384 (bit14, commutes with XOR)

    // pos: 0=B0, 1=B1, 2=A0, 3=A1 (LDS layout offsets unchanged)
#define STAGE(tile, pos) do {                                                        \
    signed char* _ld = lds + ((tile) & 1) * 65536                                    \
        + (((pos) < 2) ? (32768 + (pos) * 16384) : (((pos) - 2) * 16384))            \
        + wave * 1024;                                                               \
    const signed char* _sa = (((pos) < 2) ? Bg : Ag) + (size_t)(tile) * 128;         \
    int _o0 = ((pos) == 0 ? sB0a : (pos) == 1 ? sB1a : (pos) == 2 ? sA0a : sA1a);    \
    int _o1 = ((pos) == 0 ? sB0b : (pos) == 1 ? sB1b : (pos) == 2 ? sA0b : sA1b);    \
    __builtin_amdgcn_global_load_lds(                                                \
        (const __attribute__((address_space(1))) void*)(_sa + _o0),                  \
        (__attribute__((address_space(3))) void*)_ld, 16, 0, 0);                     \
    __builtin_amdgcn_global_load_lds(                                                \
        (const __attribute__((address_space(1))) void*)(_sa + _o1),                  \
        (__attribute__((address_space(3))) void*)(_ld + 8192), 16, 0, 0);            \
} while (0)

    i32x4 acc[8][4] = {};
    i32x4 a0[4][2], a1[4][2], b0[2][2], b1[2][2];

#define MFMA_Q(AF, BF, mo, no) do {                                                  \
    _Pragma("unroll")                                                                \
    for (int mf = 0; mf < 4; ++mf)                                                   \
        _Pragma("unroll")                                                            \
        for (int nf = 0; nf < 2; ++nf)                                               \
            _Pragma("unroll")                                                        \
            for (int kk = 0; kk < 2; ++kk)                                           \
                acc[(mo) + mf][(no) + nf] = __builtin_amdgcn_mfma_i32_16x16x64_i8(   \
                    AF[mf][kk], BF[nf][kk], acc[(mo) + mf][(no) + nf], 0, 0, 0);     \
} while (0)

#define READ_A0(buf) do {                                                            \
    _Pragma("unroll")                                                                \
    for (int mf = 0; mf < 4; ++mf) {                                                 \
        a0[mf][0] = *(const i32x4*)((buf) + ab0 + mf * 2048);                        \
        a0[mf][1] = *(const i32x4*)((buf) + ab1 + mf * 2048);                        \
    }                                                                                \
} while (0)

#define READ_A1(buf) do {                                                            \
    _Pragma("unroll")                                                                \
    for (int mf = 0; mf < 4; ++mf) {                                                 \
        a1[mf][0] = *(const i32x4*)((buf) + 16384 + ab0 + mf * 2048);                \
        a1[mf][1] = *(const i32x4*)((buf) + 16384 + ab1 + mf * 2048);                \
    }                                                                                \
} while (0)

#define READ_B0(buf) do {                                                            \
    _Pragma("unroll")                                                                \
    for (int nf = 0; nf < 2; ++nf) {                                                 \
        b0[nf][0] = *(const i32x4*)((buf) + bb0 + nf * 2048);                        \
        b0[nf][1] = *(const i32x4*)((buf) + bb1 + nf * 2048);                        \
    }                                                                                \
} while (0)

#define READ_B1(buf) do {                                                            \
    _Pragma("unroll")                                                                \
    for (int nf = 0; nf < 2; ++nf) {                                                 \
        b1[nf][0] = *(const i32x4*)((buf) + 16384 + bb0 + nf * 2048);                \
        b1[nf][1] = *(const i32x4*)((buf) + 16384 + bb1 + nf * 2048);                \
    }                                                                                \
} while (0)

    // prologue: issue order must match steady-state per-wave order:
    // B0(0),B1(0),A0(0),A1(0),B0(1),B1(1) -- then loop P0 issues A0(1).
    STAGE(0, 0); STAGE(0, 1); STAGE(0, 2); STAGE(0, 3);
    STAGE(1, 0); STAGE(1, 1);
    asm volatile("s_waitcnt vmcnt(4)" ::: "memory");   // tile0 fully landed
    BARRIER();
    READ_A0(lds);
    READ_B0(lds);

    for (int t = 0; t < NT; ++t) {
        const signed char* buf  = lds + (t & 1) * 65536;
        const signed char* bufn = lds + ((t + 1) & 1) * 65536;

        // ---- P0: read b1(t); stage(t+1,A0); q00(a0,b0); W0; bar -----------
        READ_B1(buf);
        if (t + 1 < NT) STAGE(t + 1, 2);
        __builtin_amdgcn_s_setprio(1);  MFMA_Q(a0, b0, 0, 0);
        __builtin_amdgcn_s_setprio(0);
        if (t == NT - 1) asm volatile("s_waitcnt vmcnt(0)" ::: "memory");
        else             asm volatile("s_waitcnt vmcnt(6)" ::: "memory");
        BARRIER();

        // ---- P1: read a1(t); stage(t+1,A1); q01(a0,b1); W1; bar -----------
        READ_A1(buf);
        if (t + 1 < NT) STAGE(t + 1, 3);
        __builtin_amdgcn_s_setprio(1);  MFMA_Q(a0, b1, 0, 2);
        __builtin_amdgcn_s_setprio(0);
        if (t < NT - 1) asm volatile("s_waitcnt vmcnt(2)" ::: "memory");
        BARRIER();

        // ---- P2: read a0(t+1); stage(t+2,B0); q11(a1,b1); bar -------------
        if (t + 1 < NT) READ_A0(bufn);
        if (t + 2 < NT) STAGE(t + 2, 0);
        __builtin_amdgcn_s_setprio(1);  MFMA_Q(a1, b1, 4, 2);
        __builtin_amdgcn_s_setprio(0);
        BARRIER();

        // ---- P3: stage(t+2,B1); q10(a1,b0); then read b0(t+1); bar --------
        if (t + 2 < NT) STAGE(t + 2, 1);
        __builtin_amdgcn_s_setprio(1);  MFMA_Q(a1, b0, 4, 0);
        __builtin_amdgcn_s_setprio(0);
        __builtin_amdgcn_sched_barrier(0);   // pin: b0 reload strictly after q10
        if (t + 1 < NT) READ_B0(bufn);
        BARRIER();
    }
#undef READ_B0
#undef READ_A0
#undef READ_A1
#undef READ_B1
#undef MFMA_Q
#undef STAGE

    // epilogue: out = acc * (sa * sw[o]) + bias[o]
    float sa = act_scale[0];
    int colb = lane & 15;
    int rsub = (lane >> 4) * 4;
#pragma unroll
    for (int nf = 0; nf < 4; ++nf) {
        int o = bn * 256 + wn_i * 64 + nf * 16 + colb;
        float sw = sa * wscale[o];
        float bv = bias[o];
#pragma unroll
        for (int mf = 0; mf < 8; ++mf) {
            int grow = bm * 256 + wm_i * 128 + mf * 16 + rsub;
#pragma unroll
            for (int r = 0; r < 4; ++r)
                out[(size_t)(grow + r) * N_DIM + o] = (float)acc[mf][nf][r] * sw + bv;
        }
    }
}

// ---------------------------------------------------------------------------
// insurance fallback if ws_size < 80MB (should never trigger)
// ---------------------------------------------------------------------------
__global__ void fallback_kernel(
    const float* __restrict__ x, const float* __restrict__ w,
    const float* __restrict__ bias,
    const float* __restrict__ act_scale, const float* __restrict__ wscale,
    const int* __restrict__ act_zp, const int* __restrict__ wzp,
    float* __restrict__ out)
{
    size_t idx = (size_t)blockIdx.x * blockDim.x + threadIdx.x;
    if (idx >= (size_t)M_DIM * N_DIM) return;
    int m = (int)(idx >> 12);
    int o = (int)(idx & 4095);
    float sx = act_scale[0], zx = (float)act_zp[0];
    float sw = wscale[o],    zw = (float)wzp[o];
    float acc = 0.f;
    for (int k = 0; k < K_DIM; ++k) {
        float qx = fminf(fmaxf(rintf(x[(size_t)m * K_DIM + k] / sx) + zx, -128.f), 127.f) - zx;
        float qw = fminf(fmaxf(rintf(w[(size_t)o * K_DIM + k] / sw) + zw, -128.f), 127.f) - zw;
        acc += (qx * sx) * (qw * sw);
    }
    out[idx] = acc + bias[o];
}

// ---------------------------------------------------------------------------
extern "C" void kernel_launch(void* const* d_in, const int* in_sizes, int n_in,
                              void* d_out, int out_size, void* d_ws, size_t ws_size,
                              hipStream_t stream)
{
    const float* x    = (const float*)d_in[0];
    const float* w    = (const float*)d_in[1];
    const float* bias = (const float*)d_in[2];
    const float* asc  = (const float*)d_in[3];
    const float* wsc  = (const float*)d_in[4];
    const int*   azp  = (const int*)d_in[5];
    const int*   wzp  = (const int*)d_in[6];
    float* out = (float*)d_out;

    size_t xq_bytes = (size_t)M_DIM * K_DIM;   // 64 MiB
    size_t wq_bytes = (size_t)N_DIM * K_DIM;   // 16 MiB

    if (ws_size < xq_bytes + wq_bytes) {
        int total = M_DIM * N_DIM;
        fallback_kernel<<<(total + 255) / 256, 256, 0, stream>>>(
            x, w, bias, asc, wsc, azp, wzp, out);
        return;
    }

    signed char* xq = (signed char*)d_ws;
    signed char* wq = (signed char*)d_ws + xq_bytes;

    quant_x_kernel<<<(M_DIM * (K_DIM / 16)) / 256, 256, 0, stream>>>(x, asc, azp, xq);
    quant_w_kernel<<<(N_DIM * (K_DIM / 16)) / 256, 256, 0, stream>>>(w, wsc, wzp, wq);
    gemm_i8_256<<<(M_DIM / 256) * (N_DIM / 256), 512, 0, stream>>>(
        xq, wq, bias, asc, wsc, out);
}